// Round 5
// baseline (367.834 us; speedup 1.0000x reference)
//
#include <hip/hip_runtime.h>
#include <math.h>

#define NEGV 1000000000000.0f
#define LDSTR 68   // 64 + 4 pad: keeps 16B alignment for float4 LDS reads, breaks bank conflicts

// ---------------- Kernel 1: h = x@W1+b1; RoPE -> qw,kw; bias tables ----------------
// grid 256 blocks x 256 threads; each block handles 16 rows of the 4096 (b*s) rows.
// Adds bAp[b][o][n] = bias[b][2o][n] * mask[b][n] table for k2b's 2-VALU epilogue.
__global__ __launch_bounds__(256) void k1_fused(
    const float* __restrict__ x,    // (4096, 768)
    const float* __restrict__ mask, // (4, 1024)
    const float* __restrict__ W1,   // (768, 128)
    const float* __restrict__ b1,   // (128)
    const float* __restrict__ W2,   // (128, 32)
    const float* __restrict__ b2,   // (32)
    float* __restrict__ qw,         // (4096, 64)
    float* __restrict__ kw,         // (4096, 64)
    float* __restrict__ bias,       // (4, 32, 1024)
    float* __restrict__ bAp)        // (4, 16, 1024)  = bias_even * mask
{
    __shared__ float xs[16][772];   // 16 rows x 768, +4 pad
    __shared__ float hs[16][132];
    const int t    = threadIdx.x;
    const int row0 = blockIdx.x * 16;

    // ---- stage x tile (16 x 768 = 48 KB) into LDS, float4 coalesced ----
    {
        const float4* xg = (const float4*)(x + (size_t)row0 * 768);
        #pragma unroll
        for (int it = 0; it < 12; ++it) {
            const int idx = t + it * 256;            // 0..3071
            const int r = idx / 192, c4 = idx - r * 192;
            const float4 v = xg[idx];
            *(float4*)&xs[r][c4 * 4] = v;
        }
    }
    __syncthreads();

    // ---- GEMM: thread = 2 rows x 4 cols. x from LDS (broadcast b128), W1 float4 VMEM ----
    const int jc = (t & 31) * 4;
    const int rg = (t >> 5) * 2;
    float accA[4] = {0.f,0.f,0.f,0.f};
    float accB[4] = {0.f,0.f,0.f,0.f};
    #pragma unroll 2
    for (int k = 0; k < 768; k += 4) {
        const float4 xa = *(const float4*)&xs[rg][k];
        const float4 xb = *(const float4*)&xs[rg + 1][k];
        const float xav[4] = {xa.x, xa.y, xa.z, xa.w};
        const float xbv[4] = {xb.x, xb.y, xb.z, xb.w};
        #pragma unroll
        for (int kk = 0; kk < 4; ++kk) {
            const float4 w = *(const float4*)&W1[(size_t)(k + kk) * 128 + jc];
            const float wv[4] = {w.x, w.y, w.z, w.w};
            #pragma unroll
            for (int c = 0; c < 4; ++c) {
                accA[c] = fmaf(xav[kk], wv[c], accA[c]);
                accB[c] = fmaf(xbv[kk], wv[c], accB[c]);
            }
        }
    }
    {
        const float4 bv = *(const float4*)&b1[jc];
        const float bvv[4] = {bv.x, bv.y, bv.z, bv.w};
        #pragma unroll
        for (int c = 0; c < 4; ++c) {
            hs[rg][jc + c]     = accA[c] + bvv[c];
            hs[rg + 1][jc + c] = accB[c] + bvv[c];
        }
    }
    __syncthreads();

    // ---- RoPE. qw[c]=h[2c], kw[c]=h[2c+1] ----
    for (int idx = t; idx < 16 * 64; idx += 256) {
        const int r = idx >> 6, c = idx & 63;
        const int rowg = row0 + r;
        const int s = rowg & 1023;
        const int f = c & 31;
        const float invf = exp2f(-0.4152410118609203f * (float)f); // 10000^(-f/32)
        const float ang = (float)s * invf;
        float sn, cs;
        sincosf(ang, &sn, &cs);
        const int   pc  = (c & 1) ? (c - 1) : (c + 1);
        const float sgn = (c & 1) ? sn : -sn;
        const float qv = fmaf(hs[r][2*c],     cs, hs[r][2*pc]     * sgn);
        const float kv = fmaf(hs[r][2*c + 1], cs, hs[r][2*pc + 1] * sgn);
        qw[(size_t)rowg * 64 + c] = qv;
        kw[(size_t)rowg * 64 + c] = kv;
    }

    // ---- bias[b][c][s] = (h[row].W2[:,c] + b2[c]) * 0.5 ; bAp = bias_even*mask ----
    for (int idx = t; idx < 16 * 32; idx += 256) {
        const int r = idx >> 5, c = idx & 31;
        const int rowg = row0 + r;
        const int s = rowg & 1023, bb = rowg >> 10;
        float a = 0.f;
        #pragma unroll 4
        for (int k = 0; k < 128; ++k)
            a = fmaf(hs[r][k], W2[k * 32 + c], a);
        const float v = (a + b2[c]) * 0.5f;
        bias[(size_t)(bb * 32 + c) * 1024 + s] = v;
        if ((c & 1) == 0)
            bAp[(size_t)(bb * 16 + (c >> 1)) * 1024 + s] = v * mask[bb * 1024 + s];
    }
}

// ---------------- Kernel 2a: Sc[b][m][n] = qk/8*p[n] + (p[n]-1)*NEG - causal*NEG ----------
// o-independent part. grid (16,16,4); 64x64 tile; 4x4 per thread. LDS ~35 KB -> 4 blocks/CU.
__global__ __launch_bounds__(256) void k2a_qk(
    const float* __restrict__ qw, const float* __restrict__ kw,
    const float* __restrict__ mask, float* __restrict__ Sc)
{
    __shared__ float qs[64 * LDSTR];   // [k][m]
    __shared__ float ks[64 * LDSTR];   // [k][n]
    __shared__ float padv[64];

    const int t  = threadIdx.x;
    const int n0 = blockIdx.x * 64;
    const int m0 = blockIdx.y * 64;
    const int b  = blockIdx.z;

    const float4* qg = (const float4*)(qw + (size_t)(b * 1024 + m0) * 64);
    const float4* kg = (const float4*)(kw + (size_t)(b * 1024 + n0) * 64);
    #pragma unroll
    for (int it = 0; it < 4; ++it) {
        const int idx = t + it * 256;          // 0..1023 ; = m*16 + kgp
        const int m = idx >> 4, kgp = idx & 15;
        float4 v = qg[idx];
        qs[(4*kgp + 0) * LDSTR + m] = v.x;
        qs[(4*kgp + 1) * LDSTR + m] = v.y;
        qs[(4*kgp + 2) * LDSTR + m] = v.z;
        qs[(4*kgp + 3) * LDSTR + m] = v.w;
        v = kg[idx];
        ks[(4*kgp + 0) * LDSTR + m] = v.x;
        ks[(4*kgp + 1) * LDSTR + m] = v.y;
        ks[(4*kgp + 2) * LDSTR + m] = v.z;
        ks[(4*kgp + 3) * LDSTR + m] = v.w;
    }
    if (t < 64) padv[t] = mask[b * 1024 + n0 + t];
    __syncthreads();

    const int tn = t & 15, tm = t >> 4;
    float acc[4][4];
    #pragma unroll
    for (int i = 0; i < 4; ++i)
        #pragma unroll
        for (int c = 0; c < 4; ++c) acc[i][c] = 0.f;

    #pragma unroll 8
    for (int k = 0; k < 64; ++k) {
        const float4 qv = *(const float4*)&qs[k * LDSTR + 4 * tm];
        const float4 kv = *(const float4*)&ks[k * LDSTR + 4 * tn];
        const float qa[4] = {qv.x, qv.y, qv.z, qv.w};
        const float ka[4] = {kv.x, kv.y, kv.z, kv.w};
        #pragma unroll
        for (int i = 0; i < 4; ++i)
            #pragma unroll
            for (int c = 0; c < 4; ++c)
                acc[i][c] = fmaf(qa[i], ka[c], acc[i][c]);
    }

    const float4 pv = *(const float4*)&padv[4 * tn];
    const float p[4] = {pv.x, pv.y, pv.z, pv.w};
    const int ng = n0 + 4 * tn;

    #pragma unroll
    for (int i = 0; i < 4; ++i) {
        const int mg = m0 + 4 * tm + i;
        float4 s4;
        float rv[4];
        #pragma unroll
        for (int c = 0; c < 4; ++c) {
            float kadd = (p[c] - 1.f) * NEGV;          // -(1-p)*NEG
            if (ng + c < mg) kadd -= NEGV;             // tril(-1) causal
            rv[c] = fmaf(acc[i][c] * 0.125f, p[c], kadd);
        }
        s4.x = rv[0]; s4.y = rv[1]; s4.z = rv[2]; s4.w = rv[3];
        *(float4*)&Sc[(size_t)(b * 1024 + mg) * 1024 + ng] = s4;
    }
}

// ---------------- Kernel 2b: fill-like streamer ----------------
// out[b,o,m,n] = Sc[b,m,n] + bAp[b,o,n] + bias[b,2o+1,m]*p[b,n]
// Wave = one quarter-row (256 n): every store instr is 1 KB fully contiguous (fill pattern).
// grid 2048 x 256; each wave handles 2 (b,m,nq) positions x 16 o-planes.
__global__ __launch_bounds__(256) void k2b_stream(
    const float* __restrict__ Sc, const float* __restrict__ bias,
    const float* __restrict__ bAp, const float* __restrict__ mask,
    float* __restrict__ out)
{
    const int t = threadIdx.x;
    const int l = t & 63;
    const int W = (blockIdx.x << 2) + (t >> 6);   // wave id 0..8191

    #pragma unroll
    for (int rep = 0; rep < 2; ++rep) {
        const int Wp = W + rep * 8192;            // 0..16383
        const int b  = Wp >> 12;
        const int m  = (Wp >> 2) & 1023;
        const int nq = Wp & 3;
        const int n4 = nq * 64 + l;               // float4 col 0..255

        const float4 sc4 = *(const float4*)&Sc[(size_t)(b * 1024 + m) * 1024 + n4 * 4];
        const float4 p4  = *(const float4*)&mask[b * 1024 + n4 * 4];

        #pragma unroll
        for (int o = 0; o < 16; ++o) {
            const float4 a4 = *(const float4*)&bAp[(size_t)(b * 16 + o) * 1024 + n4 * 4];
            const float  bo = bias[(size_t)(b * 32 + 2 * o + 1) * 1024 + m];
            float4 r;
            r.x = fmaf(bo, p4.x, sc4.x + a4.x);
            r.y = fmaf(bo, p4.y, sc4.y + a4.y);
            r.z = fmaf(bo, p4.z, sc4.z + a4.z);
            r.w = fmaf(bo, p4.w, sc4.w + a4.w);
            *(float4*)&out[(size_t)((b * 16 + o) * 1024 + m) * 1024 + n4 * 4] = r;
        }
    }
}

extern "C" void kernel_launch(void* const* d_in, const int* in_sizes, int n_in,
                              void* d_out, int out_size, void* d_ws, size_t ws_size,
                              hipStream_t stream) {
    const float* x    = (const float*)d_in[0];
    const float* mask = (const float*)d_in[1];
    const float* W1   = (const float*)d_in[2];
    const float* b1   = (const float*)d_in[3];
    const float* W2   = (const float*)d_in[4];
    const float* b2   = (const float*)d_in[5];
    float* out = (float*)d_out;

    float* ws   = (float*)d_ws;
    float* qw   = ws;                        // 262144 floats
    float* kw   = ws + 262144;               // 262144 floats
    float* bias = ws + 524288;               // 131072 floats (4,32,1024)
    float* bAp  = ws + 655360;               // 65536 floats  (4,16,1024)
    float* Sc   = ws + 720896;               // 4194304 floats (4,1024,1024) = 16 MB

    hipLaunchKernelGGL(k1_fused, dim3(256), dim3(256), 0, stream,
                       x, mask, W1, b1, W2, b2, qw, kw, bias, bAp);
    hipLaunchKernelGGL(k2a_qk, dim3(16, 16, 4), dim3(256), 0, stream,
                       qw, kw, mask, Sc);
    hipLaunchKernelGGL(k2b_stream, dim3(2048), dim3(256), 0, stream,
                       Sc, bias, bAp, mask, out);
}